// Round 4
// baseline (495.685 us; speedup 1.0000x reference)
//
#include <hip/hip_runtime.h>
#include <cfloat>

// VectorQuantizer: N=32768 rows, K=8192 codes, D=256, fp32.
// R2/R3 established (absmax 0): reference = numpy fp32 arithmetic;
//   d_k = fl32( fl32(x2 + wn_k) - fl32(2*m_k) ), m_k = single fp32 FMA chain
//   d ascending; first-occurrence argmin. Exact rescore of top-8 bf16-MFMA
//   candidates reproduces it bit-for-bit.
// R4: MFMA-bound rewrite of the scorer:
//   - A (x) fragments held in 128 VGPRs for the whole kernel (converted once)
//   - W negated at bf16-convert + acc init C=2^-6  =>  acc = C - m > 0,
//     uint-monotone key with NO sortable transform (3 VALU/elem selection:
//     and_or + min + med3-forming min(max))
//   - 64-col W tiles double-buffered in LDS (2x32KB), XOR-swizzled 16B
//     granules (uniform bank phases for ds_read_b128/ds_write_b128)
//   - coalesced prep kernel: LDS-staged rows, 8 lanes/row, shfl-xor tree in
//     numpy's exact pairwise order (fp-add commutativity => bit-exact)

#define DDIM 256
#define CBIAS 0.015625f   // > 2x max |m| (~7e-3 = 6.3 sigma over 2.7e8 samples)

typedef float f32x4 __attribute__((ext_vector_type(4)));
typedef short bf16x8 __attribute__((ext_vector_type(8)));

__device__ __forceinline__ unsigned short f2bf(float f) {
    unsigned u = __float_as_uint(f);
    u += 0x7FFFu + ((u >> 16) & 1u);   // RNE
    return (unsigned short)(u >> 16);
}

// ---------- fused norms (exact numpy pairwise order) + W -> -bf16 ----------
__global__ __launch_bounds__(256) void vq_prep(
    const float* __restrict__ x, const float* __restrict__ w,
    float* __restrict__ x2, float* __restrict__ wn,
    unsigned short* __restrict__ wb, int nxblocks) {
    __shared__ float rows[32 * 260];   // pitch 260: conflict-free stride-8 reads
    const int tid = threadIdx.x;
    const bool isX = (int)blockIdx.x < nxblocks;
    const int r0 = (isX ? blockIdx.x : (blockIdx.x - nxblocks)) * 32;
    const float* src = isX ? x : w;

    for (int idx = tid; idx < 32 * 64; idx += 256) {
        int r = idx >> 6, c4 = idx & 63;
        *(float4*)&rows[r * 260 + c4 * 4] =
            *(const float4*)(src + (size_t)(r0 + r) * DDIM + c4 * 4);
    }
    __syncthreads();
    {
        // numpy pairwise_sum(fl(a*a), 256) = half(128)+half(128); each half:
        // 8 stride-8 chains r_j, combined ((r0+r1)+(r2+r3))+((r4+r5)+(r6+r7)).
        // 8 lanes per row; shfl-xor tree == that exact nesting (commutativity).
        const int row = (tid >> 6) * 8 + ((tid & 63) >> 3), j = tid & 7;
        const float* a = &rows[row * 260];
        float half[2];
#pragma unroll
        for (int h = 0; h < 2; ++h) {
            const float* b = a + h * 128 + j;
            float r = __fmul_rn(b[0], b[0]);
#pragma unroll
            for (int t = 1; t < 16; ++t)
                r = __fadd_rn(r, __fmul_rn(b[8 * t], b[8 * t]));
            float p = __fadd_rn(r, __shfl_xor(r, 1, 64));
            p = __fadd_rn(p, __shfl_xor(p, 2, 64));
            p = __fadd_rn(p, __shfl_xor(p, 4, 64));
            half[h] = p;
        }
        float s = __fadd_rn(half[0], half[1]);
        if (j == 0) { if (isX) x2[r0 + row] = s; else wn[r0 + row] = s; }
    }
    if (!isX) {   // emit NEGATED bf16 W (sign-symmetric RNE: flip bit 15)
        for (int idx = tid; idx < 32 * 64; idx += 256) {
            int r = idx >> 6, c4 = idx & 63;
            float4 f = *(const float4*)&rows[r * 260 + c4 * 4];
            ushort4 o;
            o.x = (unsigned short)(f2bf(f.x) ^ 0x8000u);
            o.y = (unsigned short)(f2bf(f.y) ^ 0x8000u);
            o.z = (unsigned short)(f2bf(f.z) ^ 0x8000u);
            o.w = (unsigned short)(f2bf(f.w) ^ 0x8000u);
            *(ushort4*)(wb + (size_t)(r0 + r) * DDIM + c4 * 4) = o;
        }
    }
}

// ---------- MFMA scorer: 128 rows/block, A-in-registers, W dbuf ----------
// 512 thr = 8 waves (wr 0..1 x wc 0..3); wave tile 64 rows x 16 cols.
// Layouts (m89-verified): A row=lane&15,k=q*8+j; B col=lane&15,k=q*8+j;
// C col=lane&15,row=q*4+reg.
__global__ __launch_bounds__(512, 2) void vq_score(
    const float* __restrict__ x, const unsigned short* __restrict__ wb,
    unsigned* __restrict__ cand, int K) {
    __shared__ unsigned short Ws[2][16384];   // 2 x 32 KB
    const int tid = threadIdx.x;
    const int wave = tid >> 6, lane = tid & 63;
    const int q = lane >> 4, c = lane & 15;
    const int wr = wave >> 2, wc = wave & 3;
    const int rowBase = blockIdx.x * 128;

    // A fragments: x fp32 -> bf16, held in VGPRs for the whole kernel
    bf16x8 af[4][8];
#pragma unroll
    for (int rt = 0; rt < 4; ++rt) {
        const float* xr = x + (size_t)(rowBase + wr * 64 + rt * 16 + c) * DDIM;
#pragma unroll
        for (int ks = 0; ks < 8; ++ks) {
            const float4* px = (const float4*)(xr + ks * 32 + q * 8);
            float4 f0 = px[0], f1 = px[1];
            union { unsigned short u[8]; bf16x8 v; } pk;
            pk.u[0] = f2bf(f0.x); pk.u[1] = f2bf(f0.y);
            pk.u[2] = f2bf(f0.z); pk.u[3] = f2bf(f0.w);
            pk.u[4] = f2bf(f1.x); pk.u[5] = f2bf(f1.y);
            pk.u[6] = f2bf(f1.z); pk.u[7] = f2bf(f1.w);
            af[rt][ks] = pk.v;
        }
    }

    unsigned s0[4][4], s1[4][4];
#pragma unroll
    for (int a = 0; a < 4; ++a)
#pragma unroll
        for (int b = 0; b < 4; ++b) { s0[a][b] = 0xFFFFFFFFu; s1[a][b] = 0xFFFFFFFFu; }

    // staging map: thread -> col scol, 4 granules (16B) sg0..sg0+3, XOR swizzle
    const int scol = tid >> 3, sg0 = (tid & 7) * 4, swz = scol & 15;
    int wofs[4];
#pragma unroll
    for (int i = 0; i < 4; ++i) wofs[i] = scol * 256 + (((sg0 + i) ^ swz) * 8);
    const size_t gofs = (size_t)scol * DDIM + sg0 * 8;

    const int bcol = wc * 16 + c;
    int bofs[8];
#pragma unroll
    for (int ks = 0; ks < 8; ++ks) bofs[ks] = bcol * 256 + (((ks * 4 + q) ^ c) * 8);

    const int ktn = K >> 6;
    uint4 st[4];
    {   // preload tile 0
        const uint4* g = (const uint4*)(wb + gofs);
#pragma unroll
        for (int i = 0; i < 4; ++i) st[i] = g[i];
#pragma unroll
        for (int i = 0; i < 4; ++i) *(uint4*)&Ws[0][wofs[i]] = st[i];
    }
    __syncthreads();

    for (int kt = 0; kt < ktn; ++kt) {
        const int cur = kt & 1;
        if (kt + 1 < ktn) {   // issue next tile's loads; consumed after compute
            const uint4* g = (const uint4*)(wb + (size_t)(kt + 1) * 64 * DDIM + gofs);
#pragma unroll
            for (int i = 0; i < 4; ++i) st[i] = g[i];
        }
        f32x4 acc[4];
#pragma unroll
        for (int rt = 0; rt < 4; ++rt) acc[rt] = (f32x4){CBIAS, CBIAS, CBIAS, CBIAS};
#pragma unroll
        for (int ks = 0; ks < 8; ++ks) {
            bf16x8 bfr = *(const bf16x8*)&Ws[cur][bofs[ks]];
#pragma unroll
            for (int rt = 0; rt < 4; ++rt)
                acc[rt] = __builtin_amdgcn_mfma_f32_16x16x32_bf16(
                    af[rt][ks], bfr, acc[rt], 0, 0, 0);
        }
        // selection: acc = C - m > 0 (uint-monotone). 3 VALU/elem:
        // and_or(key) + min(s0) + min(max)=med3(s1).
        const unsigned colv = (unsigned)(kt * 64 + bcol);
#pragma unroll
        for (int rt = 0; rt < 4; ++rt)
#pragma unroll
            for (int rg = 0; rg < 4; ++rg) {
                unsigned key = (__float_as_uint(acc[rt][rg]) & 0xFFFFE000u) | colv;
                unsigned a0 = s0[rt][rg];
                unsigned mx = key > a0 ? key : a0;
                s1[rt][rg] = mx < s1[rt][rg] ? mx : s1[rt][rg];
                s0[rt][rg] = key < a0 ? key : a0;
            }
        if (kt + 1 < ktn) {
            const int nxt = cur ^ 1;
#pragma unroll
            for (int i = 0; i < 4; ++i) *(uint4*)&Ws[nxt][wofs[i]] = st[i];
            __syncthreads();
        }
    }

    // per-row merge: 64 slot-lanes x 2 keys = 128 keys/row
    __syncthreads();
    unsigned* ms = (unsigned*)Ws;   // 128 rows x 128 keys = 64 KB exactly
#pragma unroll
    for (int rt = 0; rt < 4; ++rt)
#pragma unroll
        for (int rg = 0; rg < 4; ++rg) {
            int row = wr * 64 + rt * 16 + q * 4 + rg;
            *(uint2*)&ms[row * 128 + (wc * 16 + c) * 2] =
                make_uint2(s0[rt][rg], s1[rt][rg]);
        }
    __syncthreads();
    if (tid < 128) {
        const unsigned* rowk = ms + tid * 128;
        unsigned best[8];
#pragma unroll
        for (int i = 0; i < 8; ++i) best[i] = 0xFFFFFFFFu;
        for (int i = 0; i < 128; ++i) {
            unsigned key = rowk[(i + tid) & 127];   // rotation: bank-spread
            if (key < best[7]) {
                best[7] = key;
#pragma unroll
                for (int j = 7; j > 0; --j)
                    if (best[j] < best[j - 1]) {
                        unsigned t = best[j]; best[j] = best[j - 1]; best[j - 1] = t;
                    }
            }
        }
        unsigned* out = cand + (size_t)(rowBase + tid) * 8;
#pragma unroll
        for (int i = 0; i < 8; ++i) out[i] = best[i];
    }
}

// ---------- exact fp32-chain rescore of 8 candidates (R3-verified) ----------
__global__ __launch_bounds__(256) void vq_rescore_write(
    const float* __restrict__ x, const float* __restrict__ w,
    const float* __restrict__ x2, const float* __restrict__ wn,
    const unsigned* __restrict__ cand, float* __restrict__ outq,
    float* __restrict__ outi) {
    __shared__ int winners[32];
    const int tid = threadIdx.x;
    const int lr = tid >> 3, cc = tid & 7;
    const int row = blockIdx.x * 32 + lr;

    int k = (int)(cand[(size_t)row * 8 + cc] & 0x1FFFu);
    const float* xr = x + (size_t)row * DDIM;
    const float* wr = w + (size_t)k * DDIM;
    float acc = 0.f;
#pragma unroll 8
    for (int d = 0; d < DDIM; d += 4) {
        float4 xv = *reinterpret_cast<const float4*>(xr + d);
        float4 wv = *reinterpret_cast<const float4*>(wr + d);
        acc = __fmaf_rn(xv.x, wv.x, acc);
        acc = __fmaf_rn(xv.y, wv.y, acc);
        acc = __fmaf_rn(xv.z, wv.z, acc);
        acc = __fmaf_rn(xv.w, wv.w, acc);
    }
    float dv = __fsub_rn(__fadd_rn(x2[row], wn[k]), __fmul_rn(2.0f, acc));
#pragma unroll
    for (int m = 1; m < 8; m <<= 1) {
        float od = __shfl_xor(dv, m, 64);
        int   ok = __shfl_xor(k,  m, 64);
        if (od < dv || (od == dv && ok < k)) { dv = od; k = ok; }
    }
    if (cc == 0) winners[lr] = k;
    __syncthreads();
    if (tid < 32) outi[blockIdx.x * 32 + tid] = (float)winners[tid];
    for (int u = tid; u < 32 * 64; u += 256) {
        int r = u >> 6, c4 = u & 63;
        *reinterpret_cast<float4*>(outq + (size_t)(blockIdx.x * 32 + r) * DDIM + c4 * 4) =
            *reinterpret_cast<const float4*>(w + (size_t)winners[r] * DDIM + c4 * 4);
    }
}

extern "C" void kernel_launch(void* const* d_in, const int* in_sizes, int n_in,
                              void* d_out, int out_size, void* d_ws, size_t ws_size,
                              hipStream_t stream) {
    const float* x = (const float*)d_in[0];
    const float* w = (const float*)d_in[1];
    const int N = in_sizes[0] / DDIM;   // 32768
    const int K = in_sizes[1] / DDIM;   // 8192
    float* outq = (float*)d_out;
    float* outi = outq + (size_t)N * DDIM;

    char* ws = (char*)d_ws;
    unsigned short* wb = (unsigned short*)ws;                 // K*256 bf16 = 4 MB
    float* x2   = (float*)(ws + (size_t)K * DDIM * 2);        // N floats
    float* wn   = x2 + N;                                     // K floats
    unsigned* cand = (unsigned*)(wn + K);                     // N*8 u32 = 1 MB

    const int nxblocks = N / 32;
    hipLaunchKernelGGL(vq_prep, dim3((N + K) / 32), dim3(256), 0, stream,
                       x, w, x2, wn, wb, nxblocks);
    hipLaunchKernelGGL(vq_score, dim3(N / 128), dim3(512), 0, stream,
                       x, wb, cand, K);
    hipLaunchKernelGGL(vq_rescore_write, dim3(N / 32), dim3(256), 0, stream,
                       x, w, x2, wn, cand, outq, outi);
}

// Round 5
// 299.007 us; speedup vs baseline: 1.6578x; 1.6578x over previous
//
#include <hip/hip_runtime.h>
#include <cfloat>

// VectorQuantizer: N=32768 rows, K=8192 codes, D=256, fp32.
// R2/R3 (absmax 0): reference = numpy fp32; d_k = fl32(fl32(x2+wn_k)-fl32(2*m_k)),
// m_k = single fp32 FMA chain d-ascending; first-occurrence argmin. Exact top-8
// rescore of approximate-scorer candidates reproduces it bit-for-bit.
// R4 post-mortem: __launch_bounds__ 2nd arg = min BLOCKS/CU (CUDA semantics);
// (512,2) capped VGPR at 128 -> A-fragments spilled to scratch (42 MB writes).
// R5: MX-fp8 scorer (mfma_scale 32x32x64, 4686 TF measured ceiling):
//   - X,W pre-converted to OCP e4m3 in prep (W scaled x2^13 — w~1e-4 is below
//     e4m3 subnormal range — and NEGATED; pow-2 scale cancels in argmin)
//   - A resident in 64 VGPRs (64 rows x 256 k fp8); W 128-col tiles
//     double-buffered in LDS via global_load_lds (width 16), XOR-swizzled
//   - acc init C=128 => acc = 128 - m_s in [68,188]: positive, 2 exponents,
//     uint-monotone keys (R4-validated selection: 19-bit score | 13-bit col,
//     top-2 per slot, 256 kept keys/row)
//   - A/B k-placement: any bijection applied identically to both operands
//     gives the exact dot (HW pairs same k-slots) — layout-risk-free

#define DDIM 256

typedef int   i32x8  __attribute__((ext_vector_type(8)));
typedef float f32x16 __attribute__((ext_vector_type(16)));

// ---------- numpy pairwise sum-of-squares (bit-exact, R2-verified) ----------
__device__ __forceinline__ float np_sumsq_lane(const float* __restrict__ a) {
    // caller: 8 lanes per row, lane j handles stride-8 chain j; shfl-tree
    float r = __fmul_rn(a[0], a[0]);
#pragma unroll
    for (int t = 1; t < 16; ++t)
        r = __fadd_rn(r, __fmul_rn(a[8 * t], a[8 * t]));
    return r;
}

__global__ __launch_bounds__(256) void vq_prep(
    const float* __restrict__ x, const float* __restrict__ w,
    float* __restrict__ x2, float* __restrict__ wn,
    unsigned char* __restrict__ xb8, unsigned char* __restrict__ wb8,
    int nxblocks) {
    __shared__ float rows[32 * 260];
    const int tid = threadIdx.x;
    const bool isX = (int)blockIdx.x < nxblocks;
    const int r0 = (isX ? blockIdx.x : (blockIdx.x - nxblocks)) * 32;
    const float* src = isX ? x : w;

    for (int idx = tid; idx < 32 * 64; idx += 256) {
        int r = idx >> 6, c4 = idx & 63;
        *(float4*)&rows[r * 260 + c4 * 4] =
            *(const float4*)(src + (size_t)(r0 + r) * DDIM + c4 * 4);
    }
    __syncthreads();
    {
        // numpy pairwise order: two 128-halves, each 8 stride-8 chains,
        // ((r0+r1)+(r2+r3))+((r4+r5)+(r6+r7)); shfl-xor tree == that nesting.
        const int row = (tid >> 6) * 8 + ((tid & 63) >> 3), j = tid & 7;
        const float* a = &rows[row * 260];
        float half[2];
#pragma unroll
        for (int h = 0; h < 2; ++h) {
            float r = np_sumsq_lane(a + h * 128 + j);
            float p = __fadd_rn(r, __shfl_xor(r, 1, 64));
            p = __fadd_rn(p, __shfl_xor(p, 2, 64));
            p = __fadd_rn(p, __shfl_xor(p, 4, 64));
            half[h] = p;
        }
        float s = __fadd_rn(half[0], half[1]);
        if (j == 0) { if (isX) x2[r0 + row] = s; else wn[r0 + row] = s; }
    }
    // fp8 e4m3 emission: X as-is; W scaled by -2^13 (exact pow2, negated)
    {
        const float scale = isX ? 1.0f : -8192.0f;
        unsigned char* dst = isX ? xb8 : wb8;
        for (int idx = tid; idx < 32 * 16; idx += 256) {
            int r = idx >> 4, s = idx & 15;
            const float* p = &rows[r * 260 + s * 16];
            unsigned q[4];
#pragma unroll
            for (int m = 0; m < 4; ++m) {
                unsigned v = (unsigned)__builtin_amdgcn_cvt_pk_fp8_f32(
                    p[m * 4 + 0] * scale, p[m * 4 + 1] * scale, 0, false);
                v = (unsigned)__builtin_amdgcn_cvt_pk_fp8_f32(
                    p[m * 4 + 2] * scale, p[m * 4 + 3] * scale, (int)v, true);
                q[m] = v;
            }
            *(uint4*)(dst + (size_t)(r0 + r) * DDIM + s * 16) =
                make_uint4(q[0], q[1], q[2], q[3]);
        }
    }
}

// ---------- MX-fp8 scorer: 128 rows x 8192 cols per block ----------
// 512 thr = 8 waves: wr (0..1) x wc (0..3); wave tile 64r x 32c = 2 MFMA tiles
// of 32x32x64. A resident (af 64 VGPR). W: 128c x 256k fp8 = 32 KB tiles,
// dbuf, staged by global_load_lds. C/D (32x32, shape-determined):
// col=lane&31, row=(reg&3)+8*(reg>>2)+4*(lane>>5).
__global__ __launch_bounds__(512, 1) void vq_score(
    const unsigned char* __restrict__ xb8, const unsigned char* __restrict__ wb8,
    unsigned* __restrict__ cand) {
    __shared__ __align__(16) unsigned char Ws[2][32768];
    const int tid = threadIdx.x;
    const int wave = tid >> 6, lane = tid & 63;
    const int h = lane >> 5, c32 = lane & 31;
    const int wr = wave >> 2, wc = wave & 3;
    const int rowBase = blockIdx.x * 128;

    // A fragments: 64 rows (wr group) x 256 k, fp8 -> 2rt x 4ks x 8 VGPR
    i32x8 af[2][4];
#pragma unroll
    for (int rt = 0; rt < 2; ++rt) {
        const unsigned char* xr =
            xb8 + (size_t)(rowBase + wr * 64 + rt * 32 + c32) * DDIM;
#pragma unroll
        for (int ks = 0; ks < 4; ++ks) {
            union { uint4 q[2]; i32x8 v; } u;
            u.q[0] = *(const uint4*)(xr + ks * 64 + h * 32);
            u.q[1] = *(const uint4*)(xr + ks * 64 + h * 32 + 16);
            af[rt][ks] = u.v;
        }
    }

    // staging map: slot s = (wave*4+i)*64 + lane; col=s>>4, g=s&15;
    // stored granule g holds logical granule g^(col&15)  (bank spread)
    unsigned sOfs[4]; unsigned ldsOfs[4];
#pragma unroll
    for (int i = 0; i < 4; ++i) {
        int col = (wave * 4 + i) * 4 + (lane >> 4);
        int gsrc = (lane & 15) ^ (col & 15);
        sOfs[i] = (unsigned)(col * 256 + gsrc * 16);
        ldsOfs[i] = (unsigned)((wave * 4 + i) * 1024);
    }

    unsigned s0[2][16], s1[2][16];
#pragma unroll
    for (int a = 0; a < 2; ++a)
#pragma unroll
        for (int r = 0; r < 16; ++r) { s0[a][r] = 0xFFFFFFFFu; s1[a][r] = 0xFFFFFFFFu; }

    const int bcol = wc * 32 + c32, cs = bcol & 15;
    int bofs[4][2];
#pragma unroll
    for (int ks = 0; ks < 4; ++ks) {
        int gb = ks * 4 + h * 2;
        bofs[ks][0] = bcol * 256 + ((gb) ^ cs) * 16;
        bofs[ks][1] = bcol * 256 + ((gb + 1) ^ cs) * 16;
    }

    auto stage = [&](int kt, int buf) {
        const unsigned char* g = wb8 + (size_t)kt * 32768;
#pragma unroll
        for (int i = 0; i < 4; ++i)
            __builtin_amdgcn_global_load_lds(
                (const __attribute__((address_space(1))) unsigned int*)(g + sOfs[i]),
                (__attribute__((address_space(3))) unsigned int*)(&Ws[buf][ldsOfs[i]]),
                16, 0, 0);
    };

    stage(0, 0);
    for (int kt = 0; kt < 64; ++kt) {
        const int cur = kt & 1;
        __syncthreads();   // drains stage(kt) (vmcnt0) + guards nxt-buf reuse
        if (kt + 1 < 64) stage(kt + 1, cur ^ 1);

        f32x16 acc[2];
#pragma unroll
        for (int rt = 0; rt < 2; ++rt)
#pragma unroll
            for (int r = 0; r < 16; ++r) acc[rt][r] = 128.0f;
#pragma unroll
        for (int ks = 0; ks < 4; ++ks) {
            union { uint4 q[2]; i32x8 v; } b;
            b.q[0] = *(const uint4*)&Ws[cur][bofs[ks][0]];
            b.q[1] = *(const uint4*)&Ws[cur][bofs[ks][1]];
#pragma unroll
            for (int rt = 0; rt < 2; ++rt)
                acc[rt] = __builtin_amdgcn_mfma_scale_f32_32x32x64_f8f6f4(
                    af[rt][ks], b.v, acc[rt], 0, 0,
                    0, 0x7F7F7F7F, 0, 0x7F7F7F7F);   // E8M0 127 = x1.0
        }
        // selection: acc = 128 - m_s > 0, uint-monotone; top-2 per slot
        const unsigned colv = (unsigned)(kt * 128 + bcol);
#pragma unroll
        for (int rt = 0; rt < 2; ++rt)
#pragma unroll
            for (int r = 0; r < 16; ++r) {
                unsigned key = (__float_as_uint(acc[rt][r]) & 0xFFFFE000u) | colv;
                unsigned a0 = s0[rt][r];
                unsigned mx = key > a0 ? key : a0;
                s1[rt][r] = mx < s1[rt][r] ? mx : s1[rt][r];
                s0[rt][r] = key < a0 ? key : a0;
            }
    }

    // merge: 2 passes over wr groups; Ws reused as 64 rows x 256 keys (64 KB)
    unsigned* ms = (unsigned*)Ws;
    for (int g = 0; g < 2; ++g) {
        __syncthreads();
        if (wr == g) {
#pragma unroll
            for (int rt = 0; rt < 2; ++rt)
#pragma unroll
                for (int r = 0; r < 16; ++r) {
                    int rloc = rt * 32 + (r & 3) + 8 * (r >> 2) + 4 * h;
                    *(uint2*)&ms[rloc * 256 + bcol * 2] =
                        make_uint2(s0[rt][r], s1[rt][r]);
                }
        }
        __syncthreads();
        if (tid < 64) {
            const unsigned* rowk = ms + tid * 256;
            unsigned best[8];
#pragma unroll
            for (int i = 0; i < 8; ++i) best[i] = 0xFFFFFFFFu;
            for (int i = 0; i < 256; ++i) {
                unsigned key = rowk[(i + tid * 4) & 255];   // rotated: bank spread
                if (key < best[7]) {
                    best[7] = key;
#pragma unroll
                    for (int j = 7; j > 0; --j)
                        if (best[j] < best[j - 1]) {
                            unsigned t = best[j]; best[j] = best[j - 1]; best[j - 1] = t;
                        }
                }
            }
            unsigned* out = cand + (size_t)(rowBase + g * 64 + tid) * 8;
#pragma unroll
            for (int i = 0; i < 8; ++i) out[i] = best[i];
        }
    }
}

// ---------- exact fp32-chain rescore of 8 candidates (R3-verified) ----------
__global__ __launch_bounds__(256) void vq_rescore_write(
    const float* __restrict__ x, const float* __restrict__ w,
    const float* __restrict__ x2, const float* __restrict__ wn,
    const unsigned* __restrict__ cand, float* __restrict__ outq,
    float* __restrict__ outi) {
    __shared__ int winners[32];
    const int tid = threadIdx.x;
    const int lr = tid >> 3, cc = tid & 7;
    const int row = blockIdx.x * 32 + lr;

    int k = (int)(cand[(size_t)row * 8 + cc] & 0x1FFFu);
    const float* xr = x + (size_t)row * DDIM;
    const float* wr = w + (size_t)k * DDIM;
    float acc = 0.f;
#pragma unroll 8
    for (int d = 0; d < DDIM; d += 4) {
        float4 xv = *reinterpret_cast<const float4*>(xr + d);
        float4 wv = *reinterpret_cast<const float4*>(wr + d);
        acc = __fmaf_rn(xv.x, wv.x, acc);
        acc = __fmaf_rn(xv.y, wv.y, acc);
        acc = __fmaf_rn(xv.z, wv.z, acc);
        acc = __fmaf_rn(xv.w, wv.w, acc);
    }
    float dv = __fsub_rn(__fadd_rn(x2[row], wn[k]), __fmul_rn(2.0f, acc));
#pragma unroll
    for (int m = 1; m < 8; m <<= 1) {
        float od = __shfl_xor(dv, m, 64);
        int   ok = __shfl_xor(k,  m, 64);
        if (od < dv || (od == dv && ok < k)) { dv = od; k = ok; }
    }
    if (cc == 0) winners[lr] = k;
    __syncthreads();
    if (tid < 32) outi[blockIdx.x * 32 + tid] = (float)winners[tid];
    for (int u = tid; u < 32 * 64; u += 256) {
        int r = u >> 6, c4 = u & 63;
        *reinterpret_cast<float4*>(outq + (size_t)(blockIdx.x * 32 + r) * DDIM + c4 * 4) =
            *reinterpret_cast<const float4*>(w + (size_t)winners[r] * DDIM + c4 * 4);
    }
}

extern "C" void kernel_launch(void* const* d_in, const int* in_sizes, int n_in,
                              void* d_out, int out_size, void* d_ws, size_t ws_size,
                              hipStream_t stream) {
    const float* x = (const float*)d_in[0];
    const float* w = (const float*)d_in[1];
    const int N = in_sizes[0] / DDIM;   // 32768
    const int K = in_sizes[1] / DDIM;   // 8192
    float* outq = (float*)d_out;
    float* outi = outq + (size_t)N * DDIM;

    unsigned char* xb8 = (unsigned char*)d_ws;                // N*256 = 8 MB
    unsigned char* wb8 = xb8 + (size_t)N * DDIM;              // K*256 = 2 MB
    float* x2 = (float*)(wb8 + (size_t)K * DDIM);             // N floats
    float* wn = x2 + N;                                       // K floats
    unsigned* cand = (unsigned*)(wn + K);                     // N*8 u32 = 1 MB

    hipLaunchKernelGGL(vq_prep, dim3((N + K) / 32), dim3(256), 0, stream,
                       x, w, x2, wn, xb8, wb8, N / 32);
    hipLaunchKernelGGL(vq_score, dim3(N / 128), dim3(512), 0, stream,
                       xb8, wb8, cand);
    hipLaunchKernelGGL(vq_rescore_write, dim3(N / 32), dim3(256), 0, stream,
                       x, w, x2, wn, cand, outq, outi);
}

// Round 6
// 256.293 us; speedup vs baseline: 1.9341x; 1.1667x over previous
//
#include <hip/hip_runtime.h>
#include <cfloat>

// VectorQuantizer: N=32768 rows, K=8192 codes, D=256, fp32.
// R2/R3 (absmax 0): reference = numpy fp32; d_k = fl32(fl32(x2+wn_k)-fl32(2*m_k)),
// m_k = single fp32 FMA chain d-ascending; first-occurrence argmin. Exact top-8
// rescore of approximate-scorer candidates reproduces it bit-for-bit.
// R4 post-mortem: __launch_bounds__ 2nd arg = min BLOCKS/CU; (512,2) => 128 VGPR
// cap => A-fragment spill. R5 post-mortem: 1 block/CU => barrier vmcnt(0) drain
// unhidden (~3700 of 6100 cyc/kt idle), MfmaUtil 17%.
// R6: residency fix + aux-work elimination:
//   - score: 256-thr blocks (4 waves), 64 rows, grid 512 = 2 blocks/CU
//     (LDS 2x32KB dbuf/block = 128KB/CU; launch_bounds(256,2) -> VGPR<=256)
//   - A converted fp32->fp8 IN-KERNEL (X-prep pass deleted)
//   - x2 computed inline in rescore (numpy-pairwise-exact); prep is W-only
//   - selection/keys unchanged (R5-validated): acc=128-m_s>0 uint-monotone,
//     19-bit score | 13-bit col, top-2/slot, 256 keys/row, exact top-8 rescore

#define DDIM 256

typedef int   i32x8  __attribute__((ext_vector_type(8)));
typedef float f32x16 __attribute__((ext_vector_type(16)));

// ---------- W prep: numpy-exact ||w||^2 + negated scaled fp8 ----------
__global__ __launch_bounds__(256) void vq_prep_w(
    const float* __restrict__ w, float* __restrict__ wn,
    unsigned char* __restrict__ wb8) {
    __shared__ float rows[32 * 260];
    const int tid = threadIdx.x;
    const int r0 = blockIdx.x * 32;

    for (int idx = tid; idx < 32 * 64; idx += 256) {
        int r = idx >> 6, c4 = idx & 63;
        *(float4*)&rows[r * 260 + c4 * 4] =
            *(const float4*)(w + (size_t)(r0 + r) * DDIM + c4 * 4);
    }
    __syncthreads();
    {
        // numpy pairwise_sum(fl(a*a),256): two 128-halves, each 8 stride-8
        // chains, ((r0+r1)+(r2+r3))+((r4+r5)+(r6+r7)); shfl-xor == nesting.
        const int row = (tid >> 6) * 8 + ((tid & 63) >> 3), j = tid & 7;
        const float* a = &rows[row * 260];
        float half[2];
#pragma unroll
        for (int h = 0; h < 2; ++h) {
            const float* b = a + h * 128 + j;
            float r = __fmul_rn(b[0], b[0]);
#pragma unroll
            for (int t = 1; t < 16; ++t)
                r = __fadd_rn(r, __fmul_rn(b[8 * t], b[8 * t]));
            float p = __fadd_rn(r, __shfl_xor(r, 1, 64));
            p = __fadd_rn(p, __shfl_xor(p, 2, 64));
            p = __fadd_rn(p, __shfl_xor(p, 4, 64));
            half[h] = p;
        }
        if (j == 0) wn[r0 + row] = __fadd_rn(half[0], half[1]);
    }
    // fp8 e4m3 emission, scaled by -2^13 (pow2 cancels in argmin; negation
    // folds the "-2m" sign so acc = C - m_s with C=128 init)
    for (int idx = tid; idx < 32 * 16; idx += 256) {
        int r = idx >> 4, s = idx & 15;
        const float* p = &rows[r * 260 + s * 16];
        unsigned q[4];
#pragma unroll
        for (int m = 0; m < 4; ++m) {
            unsigned v = (unsigned)__builtin_amdgcn_cvt_pk_fp8_f32(
                p[m * 4 + 0] * -8192.f, p[m * 4 + 1] * -8192.f, 0, false);
            v = (unsigned)__builtin_amdgcn_cvt_pk_fp8_f32(
                p[m * 4 + 2] * -8192.f, p[m * 4 + 3] * -8192.f, (int)v, true);
            q[m] = v;
        }
        *(uint4*)(wb8 + (size_t)(r0 + r) * DDIM + s * 16) =
            make_uint4(q[0], q[1], q[2], q[3]);
    }
}

// ---------- MX-fp8 scorer: 64 rows x 8192 cols per block, 2 blocks/CU ----------
// 256 thr = 4 waves (wc = wave = col group); wave tile 64r x 32c = 2 MFMA
// 32x32x64 tiles. A resident in VGPRs (converted in-kernel). W 128c x 256k
// = 32 KB tiles, dbuf, global_load_lds (16B), XOR-swizzled granules.
// C/D (32x32): col=lane&31, row=(reg&3)+8*(reg>>2)+4*(lane>>5)  [m74/m101].
__global__ __launch_bounds__(256, 2) void vq_score(
    const float* __restrict__ x, const unsigned char* __restrict__ wb8,
    unsigned* __restrict__ cand) {
    __shared__ __align__(16) unsigned char Ws[2][32768];
    const int tid = threadIdx.x;
    const int wave = tid >> 6, lane = tid & 63;
    const int h = lane >> 5, c32 = lane & 31;
    const int wc = wave;
    const int rowBase = blockIdx.x * 64;

    // A fragments: 64 rows x 256 k fp8, converted from fp32 global (one-time)
    i32x8 af[2][4];
#pragma unroll
    for (int rt = 0; rt < 2; ++rt) {
        const float* xr = x + (size_t)(rowBase + rt * 32 + c32) * DDIM;
#pragma unroll
        for (int ks = 0; ks < 4; ++ks) {
            const float4* p = (const float4*)(xr + ks * 64 + h * 32);
            union { int d[8]; i32x8 v; } u;
#pragma unroll
            for (int m = 0; m < 8; ++m) {
                float4 f = p[m];
                unsigned v = (unsigned)__builtin_amdgcn_cvt_pk_fp8_f32(
                    f.x, f.y, 0, false);
                v = (unsigned)__builtin_amdgcn_cvt_pk_fp8_f32(
                    f.z, f.w, (int)v, true);
                u.d[m] = (int)v;
            }
            af[rt][ks] = u.v;
        }
    }

    // staging map: 4 waves x 8 instr x 64 lanes = 2048 granules (16B) = 32 KB
    unsigned sOfs[8], ldsOfs[8];
#pragma unroll
    for (int i = 0; i < 8; ++i) {
        int slot = wave * 8 + i;                  // 0..31
        int col  = slot * 4 + (lane >> 4);        // 0..127
        int gsrc = (lane & 15) ^ (col & 15);      // XOR bank spread
        sOfs[i]   = (unsigned)(col * 256 + gsrc * 16);
        ldsOfs[i] = (unsigned)(slot * 1024);      // + lane*16 implicit
    }

    unsigned s0[2][16], s1[2][16];
#pragma unroll
    for (int a = 0; a < 2; ++a)
#pragma unroll
        for (int r = 0; r < 16; ++r) { s0[a][r] = 0xFFFFFFFFu; s1[a][r] = 0xFFFFFFFFu; }

    const int bcol = wc * 32 + c32, cs = bcol & 15;
    int bofs[4][2];
#pragma unroll
    for (int ks = 0; ks < 4; ++ks) {
        int gb = ks * 4 + h * 2;
        bofs[ks][0] = bcol * 256 + ((gb)     ^ cs) * 16;
        bofs[ks][1] = bcol * 256 + ((gb + 1) ^ cs) * 16;
    }

    auto stage = [&](int kt, int buf) {
        const unsigned char* g = wb8 + (size_t)kt * 32768;
#pragma unroll
        for (int i = 0; i < 8; ++i)
            __builtin_amdgcn_global_load_lds(
                (const __attribute__((address_space(1))) unsigned int*)(g + sOfs[i]),
                (__attribute__((address_space(3))) unsigned int*)(&Ws[buf][ldsOfs[i]]),
                16, 0, 0);
    };

    stage(0, 0);
    for (int kt = 0; kt < 64; ++kt) {
        const int cur = kt & 1;
        __syncthreads();   // drains stage(kt); guards nxt-buffer reuse
        if (kt + 1 < 64) stage(kt + 1, cur ^ 1);

        f32x16 acc[2];
#pragma unroll
        for (int rt = 0; rt < 2; ++rt)
#pragma unroll
            for (int r = 0; r < 16; ++r) acc[rt][r] = 128.0f;
#pragma unroll
        for (int ks = 0; ks < 4; ++ks) {
            union { uint4 q[2]; i32x8 v; } b;
            b.q[0] = *(const uint4*)&Ws[cur][bofs[ks][0]];
            b.q[1] = *(const uint4*)&Ws[cur][bofs[ks][1]];
#pragma unroll
            for (int rt = 0; rt < 2; ++rt)
                acc[rt] = __builtin_amdgcn_mfma_scale_f32_32x32x64_f8f6f4(
                    af[rt][ks], b.v, acc[rt], 0, 0,
                    0, 0x7F7F7F7F, 0, 0x7F7F7F7F);   // E8M0 127 = x1.0
        }
        // selection: acc = 128 - m_s > 0, uint-monotone; top-2 per slot
        const unsigned colv = (unsigned)(kt * 128 + bcol);
#pragma unroll
        for (int rt = 0; rt < 2; ++rt)
#pragma unroll
            for (int r = 0; r < 16; ++r) {
                unsigned key = (__float_as_uint(acc[rt][r]) & 0xFFFFE000u) | colv;
                unsigned a0 = s0[rt][r];
                unsigned mx = key > a0 ? key : a0;
                s1[rt][r] = mx < s1[rt][r] ? mx : s1[rt][r];
                s0[rt][r] = key < a0 ? key : a0;
            }
    }

    // merge: 64 rows x 256 keys = 64 KB (reuse Ws)
    __syncthreads();
    unsigned* ms = (unsigned*)Ws;
#pragma unroll
    for (int rt = 0; rt < 2; ++rt)
#pragma unroll
        for (int r = 0; r < 16; ++r) {
            int rloc = rt * 32 + (r & 3) + 8 * (r >> 2) + 4 * h;
            *(uint2*)&ms[rloc * 256 + bcol * 2] = make_uint2(s0[rt][r], s1[rt][r]);
        }
    __syncthreads();
    if (tid < 64) {
        const uint4* rowk = (const uint4*)(ms + tid * 256);
        unsigned best[8];
#pragma unroll
        for (int i = 0; i < 8; ++i) best[i] = 0xFFFFFFFFu;
        for (int i = 0; i < 64; ++i) {
            uint4 qv = rowk[(i + tid) & 63];   // rotated: bank spread
            unsigned kk[4] = {qv.x, qv.y, qv.z, qv.w};
#pragma unroll
            for (int e = 0; e < 4; ++e) {
                unsigned key = kk[e];
                if (key < best[7]) {
                    best[7] = key;
#pragma unroll
                    for (int j = 7; j > 0; --j)
                        if (best[j] < best[j - 1]) {
                            unsigned t = best[j]; best[j] = best[j - 1]; best[j - 1] = t;
                        }
                }
            }
        }
        unsigned* out = cand + (size_t)(rowBase + tid) * 8;
#pragma unroll
        for (int i = 0; i < 8; ++i) out[i] = best[i];
    }
}

// ---------- exact rescore (fp32 chain, R3-verified) + inline numpy x2 ----------
__global__ __launch_bounds__(256) void vq_rescore_write(
    const float* __restrict__ x, const float* __restrict__ w,
    const float* __restrict__ wn, const unsigned* __restrict__ cand,
    float* __restrict__ outq, float* __restrict__ outi) {
    __shared__ int winners[32];
    const int tid = threadIdx.x;
    const int lr = tid >> 3, cc = tid & 7;
    const int row = blockIdx.x * 32 + lr;

    int k = (int)(cand[(size_t)row * 8 + cc] & 0x1FFFu);
    const float* xr = x + (size_t)row * DDIM;
    const float* wr = w + (size_t)k * DDIM;
    // dot: single fp32 fmaf chain d-ascending (BLAS-exact, R2/R3-verified)
    // x2: numpy pairwise (two halves, 8 stride-8 chains, exact nesting)
    float dot = 0.f;
    float half[2];
#pragma unroll
    for (int hh = 0; hh < 2; ++hh) {
        float r[8];
#pragma unroll
        for (int t = 0; t < 16; ++t) {
            const int d = hh * 128 + t * 8;
            float4 xa = *(const float4*)(xr + d);
            float4 xb = *(const float4*)(xr + d + 4);
            float4 wa = *(const float4*)(wr + d);
            float4 wb = *(const float4*)(wr + d + 4);
            dot = __fmaf_rn(xa.x, wa.x, dot); dot = __fmaf_rn(xa.y, wa.y, dot);
            dot = __fmaf_rn(xa.z, wa.z, dot); dot = __fmaf_rn(xa.w, wa.w, dot);
            dot = __fmaf_rn(xb.x, wb.x, dot); dot = __fmaf_rn(xb.y, wb.y, dot);
            dot = __fmaf_rn(xb.z, wb.z, dot); dot = __fmaf_rn(xb.w, wb.w, dot);
            if (t == 0) {
                r[0] = __fmul_rn(xa.x, xa.x); r[1] = __fmul_rn(xa.y, xa.y);
                r[2] = __fmul_rn(xa.z, xa.z); r[3] = __fmul_rn(xa.w, xa.w);
                r[4] = __fmul_rn(xb.x, xb.x); r[5] = __fmul_rn(xb.y, xb.y);
                r[6] = __fmul_rn(xb.z, xb.z); r[7] = __fmul_rn(xb.w, xb.w);
            } else {
                r[0] = __fadd_rn(r[0], __fmul_rn(xa.x, xa.x));
                r[1] = __fadd_rn(r[1], __fmul_rn(xa.y, xa.y));
                r[2] = __fadd_rn(r[2], __fmul_rn(xa.z, xa.z));
                r[3] = __fadd_rn(r[3], __fmul_rn(xa.w, xa.w));
                r[4] = __fadd_rn(r[4], __fmul_rn(xb.x, xb.x));
                r[5] = __fadd_rn(r[5], __fmul_rn(xb.y, xb.y));
                r[6] = __fadd_rn(r[6], __fmul_rn(xb.w == xb.w ? xb.z : xb.z, xb.z));
                r[7] = __fadd_rn(r[7], __fmul_rn(xb.w, xb.w));
            }
        }
        half[hh] = __fadd_rn(__fadd_rn(__fadd_rn(r[0], r[1]), __fadd_rn(r[2], r[3])),
                             __fadd_rn(__fadd_rn(r[4], r[5]), __fadd_rn(r[6], r[7])));
    }
    float x2v = __fadd_rn(half[0], half[1]);
    float dv = __fsub_rn(__fadd_rn(x2v, wn[k]), __fmul_rn(2.0f, dot));
    // lexicographic (dv,k) min across 8 candidate lanes (first-occurrence)
#pragma unroll
    for (int m = 1; m < 8; m <<= 1) {
        float od = __shfl_xor(dv, m, 64);
        int   ok = __shfl_xor(k,  m, 64);
        if (od < dv || (od == dv && ok < k)) { dv = od; k = ok; }
    }
    if (cc == 0) winners[lr] = k;
    __syncthreads();
    if (tid < 32) outi[blockIdx.x * 32 + tid] = (float)winners[tid];
    for (int u = tid; u < 32 * 64; u += 256) {
        int r = u >> 6, c4 = u & 63;
        *reinterpret_cast<float4*>(outq + (size_t)(blockIdx.x * 32 + r) * DDIM + c4 * 4) =
            *reinterpret_cast<const float4*>(w + (size_t)winners[r] * DDIM + c4 * 4);
    }
}

extern "C" void kernel_launch(void* const* d_in, const int* in_sizes, int n_in,
                              void* d_out, int out_size, void* d_ws, size_t ws_size,
                              hipStream_t stream) {
    const float* x = (const float*)d_in[0];
    const float* w = (const float*)d_in[1];
    const int N = in_sizes[0] / DDIM;   // 32768
    const int K = in_sizes[1] / DDIM;   // 8192
    float* outq = (float*)d_out;
    float* outi = outq + (size_t)N * DDIM;

    unsigned char* wb8 = (unsigned char*)d_ws;                // K*256 = 2 MB
    float* wn = (float*)(wb8 + (size_t)K * DDIM);             // K floats
    unsigned* cand = (unsigned*)(wn + K);                     // N*8 u32 = 1 MB

    hipLaunchKernelGGL(vq_prep_w, dim3(K / 32), dim3(256), 0, stream, w, wn, wb8);
    hipLaunchKernelGGL(vq_score, dim3(N / 64), dim3(256), 0, stream, x, wb8, cand);
    hipLaunchKernelGGL(vq_rescore_write, dim3(N / 32), dim3(256), 0, stream,
                       x, w, wn, cand, outq, outi);
}